// Round 3
// baseline (1585.005 us; speedup 1.0000x reference)
//
#include <hip/hip_runtime.h>
#include <hip/hip_bf16.h>

// R3: inputs are FP32 (reference setup_inputs dtype), output fp32 scalar.
// R1/R2 NaN root cause: fp32 buffers read as bf16 -> mantissa halfwords hit
// bf16-NaN encodings (~0.8%/halfword) -> qkv all-NaN -> loss NaN.
// Pipeline: transpose+cvt weights (fp32->bf16 [N][K]) -> gemm_qkv (gathered
// fp32 A staged via global_load_lds, v_perm RTZ cvt to bf16 frags; B bf16;
// MFMA 128x128) -> attn (batch-dim 32x32 per (l,head), bf16 MFMA, in-place
// over q slab) -> gemm_out_logits (residual + Wf reduction fused, fp32 reads,
// atomic logits) -> loss_k (fp32 out).

typedef __attribute__((ext_vector_type(8))) short short8;   // 8 x bf16
typedef __attribute__((ext_vector_type(4))) float f32x4;

#define GLB_AS __attribute__((address_space(1)))
#define LDS_AS __attribute__((address_space(3)))

__device__ __forceinline__ float b2f(unsigned short u) {
    union { unsigned int i; float f; } v; v.i = ((unsigned int)u) << 16; return v.f;
}
__device__ __forceinline__ unsigned short f2b(float f) {
    union { float f; unsigned int i; } v; v.f = f;
    unsigned int u = v.i;
    u += 0x7fffu + ((u >> 16) & 1u);   // RNE
    return (unsigned short)(u >> 16);
}
__device__ __forceinline__ unsigned int fbits(float f) {
    union { float f; unsigned int i; } v; v.f = f; return v.i;
}
// pack hi16(a0..a3,b0..b3) -> short8 bf16 (RTZ truncation), via v_perm_b32
__device__ __forceinline__ short8 pack_bf16_rtz(f32x4 a, f32x4 b) {
    union { unsigned int u[4]; short8 s; } r;
    r.u[0] = __builtin_amdgcn_perm(fbits(a[1]), fbits(a[0]), 0x07060302u);
    r.u[1] = __builtin_amdgcn_perm(fbits(a[3]), fbits(a[2]), 0x07060302u);
    r.u[2] = __builtin_amdgcn_perm(fbits(b[1]), fbits(b[0]), 0x07060302u);
    r.u[3] = __builtin_amdgcn_perm(fbits(b[3]), fbits(b[2]), 0x07060302u);
    return r.s;
}

__device__ __forceinline__ void gload_lds16(const void* src, void* ldsDst) {
    // 16B/lane async global->LDS; LDS dest = wave-uniform base + lane*16
    __builtin_amdgcn_global_load_lds((const GLB_AS void*)src, (LDS_AS void*)ldsDst, 16, 0, 0);
}

// ---------------------------------------------------------------------------
// Transpose fp32 [rows][cols] -> bf16 [cols][rows]  (weights to B^T=[N][K])
// ---------------------------------------------------------------------------
__global__ __launch_bounds__(256) void transpose_f32_bf16(
    const float* __restrict__ in, unsigned short* __restrict__ out,
    int rows, int cols)
{
    __shared__ float tile[32][33];
    const int c0 = blockIdx.x << 5, r0 = blockIdx.y << 5;
    const int tx = threadIdx.x, ty = threadIdx.y;
#pragma unroll
    for (int rr = ty; rr < 32; rr += 8)
        tile[rr][tx] = in[(size_t)(r0 + rr) * cols + (c0 + tx)];
    __syncthreads();
#pragma unroll
    for (int rr = ty; rr < 32; rr += 8)
        out[(size_t)(c0 + rr) * rows + (r0 + tx)] = f2b(tile[tx][rr]);
}

__global__ void zero_logits(float* __restrict__ logits) {
    logits[threadIdx.x] = 0.0f;   // 64 floats
}

// ---------------------------------------------------------------------------
// GEMM1: qkv[m][n] = sum_k embed[x[m]][k] * WT[n][k]  (M=65536,N=3072,K=1024)
// A: fp32 gathered, staged to LDS as 8x16B chunks/row, chunk slot s=c^(row&7)
//    -> 2-way bank aliasing only on the fragment reads (free per m136).
// B: bf16, 4x16B chunks/row, slot s=g^((row>>1)&3).
// 4 waves (2x2 of 64x64), mfma_f32_16x16x32_bf16, A frags cvt'd via v_perm.
// ---------------------------------------------------------------------------
__global__ __launch_bounds__(256) void gemm_qkv(
    const int* __restrict__ x, const float* __restrict__ embed,
    const unsigned short* __restrict__ WT, unsigned short* __restrict__ qkv)
{
    __shared__ __align__(16) float Asf[4096];           // 128 rows * 8 chunks * 4 floats (16KB)
    __shared__ __align__(16) unsigned short Bs[4096];   // 128 rows * 4 chunks * 8 bf16 (8KB)
    __shared__ int xs[128];

    const int tid = threadIdx.x;
    const int lane = tid & 63;
    const int wv = tid >> 6;
    const int wm = wv >> 1, wn = wv & 1;
    const int m0 = blockIdx.y << 7;
    const int n0 = blockIdx.x << 7;
    const int r = lane & 15, q4 = lane >> 4;

    if (tid < 128) xs[tid] = x[m0 + tid];
    __syncthreads();

    // loop-invariant staging sources
    const float* baseA[4];
#pragma unroll
    for (int u = 0; u < 4; ++u) {
        int slot = wv * 256 + u * 64 + lane;      // [0,1024): row=slot>>3, s=slot&7
        int row = slot >> 3;
        int c = (slot & 7) ^ (row & 7);           // source k-chunk (4 floats)
        baseA[u] = embed + (size_t)xs[row] * 1024 + c * 4;
    }
    const unsigned short* baseB[2];
#pragma unroll
    for (int t = 0; t < 2; ++t) {
        int slot = wv * 128 + t * 64 + lane;      // [0,512): row=slot>>2, s=slot&3
        int row = slot >> 2;
        int g = (slot & 3) ^ ((row >> 1) & 3);    // source k-chunk (8 bf16)
        baseB[t] = WT + (((size_t)(n0 + row)) << 10) + g * 8;
    }

    f32x4 acc[4][4];
#pragma unroll
    for (int i = 0; i < 4; ++i)
#pragma unroll
        for (int j = 0; j < 4; ++j) acc[i][j] = (f32x4){0.f, 0.f, 0.f, 0.f};

    for (int kt = 0; kt < 1024; kt += 32) {
        __syncthreads();
#pragma unroll
        for (int u = 0; u < 4; ++u)
            gload_lds16(baseA[u] + kt, Asf + (size_t)(wv * 256 + u * 64) * 4);
#pragma unroll
        for (int t = 0; t < 2; ++t)
            gload_lds16(baseB[t] + kt, Bs + (size_t)(wv * 128 + t * 64) * 8);
        __syncthreads();

        short8 af[4], bfr[4];
#pragma unroll
        for (int i = 0; i < 4; ++i) {
            int lrow = wm * 64 + i * 16 + r;
            int sw = lrow & 7;
            f32x4 fa0 = *(const f32x4*)(Asf + (size_t)(lrow * 8 + ((2 * q4) ^ sw)) * 4);
            f32x4 fa1 = *(const f32x4*)(Asf + (size_t)(lrow * 8 + ((2 * q4 + 1) ^ sw)) * 4);
            af[i] = pack_bf16_rtz(fa0, fa1);
        }
#pragma unroll
        for (int j = 0; j < 4; ++j) {
            int lrow = wn * 64 + j * 16 + r;
            int slot = lrow * 4 + (q4 ^ ((lrow >> 1) & 3));
            bfr[j] = *(const short8*)(Bs + (size_t)slot * 8);
        }
#pragma unroll
        for (int i = 0; i < 4; ++i)
#pragma unroll
            for (int j = 0; j < 4; ++j)
                acc[i][j] = __builtin_amdgcn_mfma_f32_16x16x32_bf16(af[i], bfr[j], acc[i][j], 0, 0, 0);
    }

    // epilogue: C/D layout col=lane&15, row=q4*4+reg (m89-verified)
#pragma unroll
    for (int i = 0; i < 4; ++i) {
        int lmb = wm * 64 + i * 16 + q4 * 4;
#pragma unroll
        for (int j = 0; j < 4; ++j) {
            int ln = n0 + wn * 64 + j * 16 + r;
#pragma unroll
            for (int rg = 0; rg < 4; ++rg) {
                int m = m0 + lmb + rg;
                qkv[(size_t)m * 3072 + ln] = f2b(acc[i][j][rg]);
            }
        }
    }
}

// ---------------------------------------------------------------------------
// Attention over the batch dim. 1 wave per (l, head). qkv rows m=b*2048+l,
// cols: q=[0,1024) k=[1024,2048) v=[2048,3072), head slab nh*64+d.
// S=QK^T (8 mfma), softmax over j in-registers (16-lane shfl), P->LDS->A-frag,
// V^T in LDS, PV (8 mfma). att overwrites the q slab in place.
// ---------------------------------------------------------------------------
__global__ __launch_bounds__(256) void attn(unsigned short* __restrict__ qkv)
{
    __shared__ __align__(16) unsigned short Vt[4][64 * 40]; // per-wave V^T [d][j], pad 40
    __shared__ __align__(16) unsigned short Ps[4][32 * 40]; // per-wave P [i][j], pad 40
    const int tid = threadIdx.x, lane = tid & 63, wv = tid >> 6;
    const int flat = (blockIdx.x << 2) + wv;     // 0..32767
    const int l = flat >> 4, nh = flat & 15;
    const int r = lane & 15, q4 = lane >> 4;
    const size_t ROWB = (size_t)2048 * 3072;     // batch stride in elements

    unsigned short* vt = Vt[wv];
    unsigned short* ps = Ps[wv];

    unsigned short* qb = qkv + (size_t)l * 3072 + nh * 64;
    const unsigned short* kb = qb + 1024;
    const unsigned short* vb = qb + 2048;

    // stage V^T: lane=d, pack (j,j+1) into a dword -> conflict-free b32 writes
#pragma unroll
    for (int p = 0; p < 16; ++p) {
        unsigned short v0 = vb[(size_t)(2 * p) * ROWB + lane];
        unsigned short v1 = vb[(size_t)(2 * p + 1) * ROWB + lane];
        *(unsigned int*)(vt + lane * 40 + 2 * p) = (unsigned int)v0 | ((unsigned int)v1 << 16);
    }

    // Q/K fragments straight from global: per instr 16 rows x 64B segments
    short8 aQ[2][2], bK[2][2];
#pragma unroll
    for (int it = 0; it < 2; ++it)
#pragma unroll
        for (int ks = 0; ks < 2; ++ks) {
            aQ[it][ks] = *(const short8*)(qb + (size_t)(it * 16 + r) * ROWB + ks * 32 + q4 * 8);
            bK[it][ks] = *(const short8*)(kb + (size_t)(it * 16 + r) * ROWB + ks * 32 + q4 * 8);
        }

    f32x4 S[2][2];
#pragma unroll
    for (int it = 0; it < 2; ++it)
#pragma unroll
        for (int jt = 0; jt < 2; ++jt) {
            f32x4 z = (f32x4){0.f, 0.f, 0.f, 0.f};
            z = __builtin_amdgcn_mfma_f32_16x16x32_bf16(aQ[it][0], bK[jt][0], z, 0, 0, 0);
            z = __builtin_amdgcn_mfma_f32_16x16x32_bf16(aQ[it][1], bK[jt][1], z, 0, 0, 0);
            S[it][jt] = z;
        }

    // softmax over j (row i = it*16 + q4*4 + rg; its 32 cols live in 16 lanes x 2 jt)
#pragma unroll
    for (int it = 0; it < 2; ++it)
#pragma unroll
        for (int rg = 0; rg < 4; ++rg) {
            float s0 = S[it][0][rg] * 0.125f;
            float s1 = S[it][1][rg] * 0.125f;
            float mx = fmaxf(s0, s1);
#pragma unroll
            for (int d = 1; d < 16; d <<= 1) mx = fmaxf(mx, __shfl_xor(mx, d, 64));
            float e0 = __expf(s0 - mx), e1 = __expf(s1 - mx);
            float sm = e0 + e1;
#pragma unroll
            for (int d = 1; d < 16; d <<= 1) sm += __shfl_xor(sm, d, 64);
            float inv = 1.0f / sm;
            int i = it * 16 + q4 * 4 + rg;
            ps[i * 40 + r]      = f2b(e0 * inv);
            ps[i * 40 + 16 + r] = f2b(e1 * inv);
        }

    __asm__ volatile("s_waitcnt lgkmcnt(0)" ::: "memory");  // Vt + Ps visible (same wave)

    short8 aP[2], bV[4];
#pragma unroll
    for (int it = 0; it < 2; ++it)
        aP[it] = *(const short8*)(ps + (it * 16 + r) * 40 + q4 * 8);
#pragma unroll
    for (int dt = 0; dt < 4; ++dt)
        bV[dt] = *(const short8*)(vt + (dt * 16 + r) * 40 + q4 * 8);

    f32x4 O[2][4];
#pragma unroll
    for (int it = 0; it < 2; ++it)
#pragma unroll
        for (int dt = 0; dt < 4; ++dt) {
            f32x4 z = (f32x4){0.f, 0.f, 0.f, 0.f};
            O[it][dt] = __builtin_amdgcn_mfma_f32_16x16x32_bf16(aP[it], bV[dt], z, 0, 0, 0);
        }

    // att -> q slab (in place; this wave already consumed its Q)
#pragma unroll
    for (int it = 0; it < 2; ++it)
#pragma unroll
        for (int dt = 0; dt < 4; ++dt)
#pragma unroll
            for (int rg = 0; rg < 4; ++rg) {
                int i = it * 16 + q4 * 4 + rg;
                qb[(size_t)i * ROWB + dt * 16 + r] = f2b(O[it][dt][rg]);
            }
}

// ---------------------------------------------------------------------------
// GEMM2: out[m][e] = h[m][e] + sum_k att[m][k]*WoT[e][k]; fused logits:
// logits[b][c] += sum_e out[m][e]*Wf[l*1024+e][c]. embed/Wf read as fp32.
// ---------------------------------------------------------------------------
__global__ __launch_bounds__(256) void gemm_out_logits(
    const int* __restrict__ x, const float* __restrict__ embed,
    const unsigned short* __restrict__ qkv, const unsigned short* __restrict__ WoT,
    const float* __restrict__ Wf, float* __restrict__ logits)
{
    __shared__ __align__(16) unsigned short As[4096];
    __shared__ __align__(16) unsigned short Bs[4096];
    __shared__ int xs[128];
    __shared__ float red[2];

    const int tid = threadIdx.x;
    const int lane = tid & 63;
    const int wv = tid >> 6;
    const int wm = wv >> 1, wn = wv & 1;
    const int m0 = blockIdx.y << 7;
    const int n0 = blockIdx.x << 7;
    const int r = lane & 15, q4 = lane >> 4;

    if (tid < 128) xs[tid] = x[m0 + tid];
    if (tid == 0) { red[0] = 0.f; red[1] = 0.f; }
    __syncthreads();

    const unsigned short* baseA[2];
    const unsigned short* baseB[2];
#pragma unroll
    for (int t = 0; t < 2; ++t) {
        int slot = wv * 128 + t * 64 + lane;
        int row = slot >> 2;
        int g = (slot & 3) ^ ((row >> 1) & 3);
        baseA[t] = qkv + (size_t)(m0 + row) * 3072 + g * 8;   // att in cols [0,1024)
        baseB[t] = WoT + (((size_t)(n0 + row)) << 10) + g * 8;
    }

    f32x4 acc[4][4];
#pragma unroll
    for (int i = 0; i < 4; ++i)
#pragma unroll
        for (int j = 0; j < 4; ++j) acc[i][j] = (f32x4){0.f, 0.f, 0.f, 0.f};

    for (int kt = 0; kt < 1024; kt += 32) {
        __syncthreads();
#pragma unroll
        for (int t = 0; t < 2; ++t) {
            gload_lds16(baseA[t] + kt, As + (size_t)(wv * 128 + t * 64) * 8);
            gload_lds16(baseB[t] + kt, Bs + (size_t)(wv * 128 + t * 64) * 8);
        }
        __syncthreads();

        short8 af[4], bfr[4];
#pragma unroll
        for (int i = 0; i < 4; ++i) {
            int lrow = wm * 64 + i * 16 + r;
            int slot = lrow * 4 + (q4 ^ ((lrow >> 1) & 3));
            af[i] = *(const short8*)(As + (size_t)slot * 8);
        }
#pragma unroll
        for (int j = 0; j < 4; ++j) {
            int lrow = wn * 64 + j * 16 + r;
            int slot = lrow * 4 + (q4 ^ ((lrow >> 1) & 3));
            bfr[j] = *(const short8*)(Bs + (size_t)slot * 8);
        }
#pragma unroll
        for (int i = 0; i < 4; ++i)
#pragma unroll
            for (int j = 0; j < 4; ++j)
                acc[i][j] = __builtin_amdgcn_mfma_f32_16x16x32_bf16(af[i], bfr[j], acc[i][j], 0, 0, 0);
    }

    // epilogue: residual (fp32 embed gather) + Wf (fp32) reduction
    float c0 = 0.f, c1 = 0.f;
#pragma unroll
    for (int i = 0; i < 4; ++i) {
        int lmb = wm * 64 + i * 16 + q4 * 4;
#pragma unroll
        for (int j = 0; j < 4; ++j) {
            int e = n0 + wn * 64 + j * 16 + r;
#pragma unroll
            for (int rg = 0; rg < 4; ++rg) {
                int lm = lmb + rg;
                int m = m0 + lm;
                int ll = m & 2047;
                float hv = embed[(size_t)xs[lm] * 1024 + e];
                float outv = acc[i][j][rg] + hv;
                const float* wfp = Wf + ((size_t)(ll << 10) + e) * 2;
                c0 += outv * wfp[0];
                c1 += outv * wfp[1];
            }
        }
    }
#pragma unroll
    for (int d = 1; d < 64; d <<= 1) {
        c0 += __shfl_xor(c0, d, 64);
        c1 += __shfl_xor(c1, d, 64);
    }
    __syncthreads();
    if (lane == 0) { atomicAdd(&red[0], c0); atomicAdd(&red[1], c1); }
    __syncthreads();
    if (tid == 0) {
        int b = m0 >> 11;
        atomicAdd(&logits[b * 2 + 0], red[0]);
        atomicAdd(&logits[b * 2 + 1], red[1]);
    }
}

// ---------------------------------------------------------------------------
// Loss: -mean_b( log_softmax(logits[b]+bf)[y_b] ), C=2. Output fp32 scalar.
// ---------------------------------------------------------------------------
__global__ void loss_k(const float* __restrict__ logits, const int* __restrict__ y,
                       const float* __restrict__ bfb, float* __restrict__ out)
{
    const int t = threadIdx.x;
    float contrib = 0.f;
    if (t < 32) {
        float l0 = logits[t * 2 + 0] + bfb[0];
        float l1 = logits[t * 2 + 1] + bfb[1];
        float mx = fmaxf(l0, l1);
        float lse = mx + logf(expf(l0 - mx) + expf(l1 - mx));
        float chosen = (y[t] == 0) ? l0 : l1;
        contrib = -(chosen - lse) * (1.0f / 32.0f);
    }
#pragma unroll
    for (int d = 1; d < 64; d <<= 1) contrib += __shfl_xor(contrib, d, 64);
    if (t == 0) *out = contrib;    // fp32 output
}

// ---------------------------------------------------------------------------
extern "C" void kernel_launch(void* const* d_in, const int* in_sizes, int n_in,
                              void* d_out, int out_size, void* d_ws, size_t ws_size,
                              hipStream_t stream) {
    const int* x      = (const int*)d_in[0];
    const int* y      = (const int*)d_in[1];
    const float* emb  = (const float*)d_in[2];
    const float* Wq   = (const float*)d_in[3];
    const float* Wkv  = (const float*)d_in[4];
    const float* Wo   = (const float*)d_in[5];
    const float* Wf   = (const float*)d_in[6];
    const float* bfb  = (const float*)d_in[7];

    char* ws = (char*)d_ws;
    unsigned short* qkv    = (unsigned short*)ws;                        // 384 MB bf16
    unsigned short* WqkvT  = (unsigned short*)(ws + 402653184);          // [3072][1024] bf16
    unsigned short* WoT    = (unsigned short*)(ws + 408944640);          // [1024][1024] bf16
    float*          logits = (float*)(ws + 411041792);                   // [32][2] fp32
    float*          out    = (float*)d_out;

    zero_logits<<<1, 64, 0, stream>>>(logits);

    transpose_f32_bf16<<<dim3(32, 32), dim3(32, 8), 0, stream>>>(Wq, WqkvT, 1024, 1024);
    transpose_f32_bf16<<<dim3(64, 32), dim3(32, 8), 0, stream>>>(Wkv, WqkvT + 1024 * 1024, 1024, 2048);
    transpose_f32_bf16<<<dim3(32, 32), dim3(32, 8), 0, stream>>>(Wo, WoT, 1024, 1024);

    gemm_qkv<<<dim3(24, 512), 256, 0, stream>>>(x, emb, WqkvT, qkv);
    attn<<<8192, 256, 0, stream>>>(qkv);
    gemm_out_logits<<<dim3(8, 512), 256, 0, stream>>>(x, emb, qkv, WoT, Wf, logits);
    loss_k<<<1, 64, 0, stream>>>(logits, y, bfb, out);
}